// Round 9
// baseline (75.166 us; speedup 1.0000x reference)
//
#include <hip/hip_runtime.h>
#include <math.h>

#define EDIM 128
#define NATOM 128
#define NBATCH 512
#define THREADS 1024
#define ROWLEN 257

// dynamic LDS layout (bytes)
#define RAWSZ 32896                  // 32 rows x 257 f32 per chunk
#define PPH  65792                   // x/X bf16 plane (32KB)
#define PQH  98560                   // k/K bf16 plane (32KB)
#define LDS_TOTAL 131328

typedef __attribute__((ext_vector_type(8))) short bf16x8;           // 8 bf16 (4 VGPRs)
typedef __attribute__((ext_vector_type(4))) float f32x4;            // MFMA C/D frag
typedef __attribute__((ext_vector_type(4))) unsigned short u16x4;   // 8B packed bf16

__device__ __forceinline__ unsigned short f2bf(float f) {       // RNE float->bf16
    unsigned u = __float_as_uint(f);
    u += 0x7FFFu + ((u >> 16) & 1u);
    return (unsigned short)(u >> 16);
}
__device__ __forceinline__ float bf2f(unsigned short h) {
    return __uint_as_float(((unsigned)h) << 16);
}
// 1-op RNE f32->bf16 via HW pack convert (src0==src1 -> order-immune)
__device__ __forceinline__ unsigned short cvt1(float x) {
    unsigned r;
    asm("v_cvt_pk_bf16_f32 %0, %1, %1" : "=v"(r) : "v"(x));
    return (unsigned short)r;
}
__device__ __forceinline__ float fast_ssp(float x) {            // softplus(x)-log2, stable
    return fmaxf(x, 0.f) + __logf(1.f + __expf(-fabsf(x))) - 0.69314718055994531f;
}
// XOR swizzle on a row-major [128][256B] bf16 plane; phase decorrelates X vs K plane.
__device__ __forceinline__ int swzp(int row, int cbyte, int phase) {
    return row * 256 + ((cbyte ^ phase) ^ ((row & 7) << 4));
}

// address-space casts for global_load_lds
#define GLD(p)  ((const __attribute__((address_space(1))) void*)(const void*)(p))
#define LDSP(p) ((__attribute__((address_space(3))) void*)(void*)(p))
#define SB()    __builtin_amdgcn_sched_barrier(0)

__global__ void wsplit_kernel(const float* __restrict__ Wx,
                              const float* __restrict__ Wk,
                              unsigned short* __restrict__ ws) {
    int g = blockIdx.x * 256 + threadIdx.x;          // 0..32767
    const float* src = (g < 16384) ? Wx : Wk;
    int idx = g & 16383;
    float v = src[idx];
    unsigned short h = f2bf(v);
    unsigned short l = f2bf(v - bf2f(h));
    int base = (g < 16384) ? 0 : 32768;
    ws[base + idx] = h;
    ws[base + 16384 + idx] = l;
}

__global__ void __launch_bounds__(THREADS, 4)   // VGPR cap 128
gen_actions_kernel(const float* __restrict__ kx,
                   const float* __restrict__ pos,
                   const float* __restrict__ mask,
                   const float* __restrict__ scale_ptr,
                   const float* __restrict__ evala,
                   const float* __restrict__ bx,
                   const float* __restrict__ bk,
                   const unsigned short* __restrict__ ws,
                   float* __restrict__ out)
{
    extern __shared__ char lds[];
    __shared__ float posXs[NATOM], posYs[NATOM], posZs[NATOM], lsBs[NATOM];
    __shared__ float amBs[NATOM * 3];
    __shared__ float redBs[2];
    __shared__ int   cntBs[2];

    const int b = blockIdx.x;
    const int t = threadIdx.x;
    const int lane = t & 63;
    const int w = t >> 6;            // wave 0..15
    const int wr = w >> 2;           // M tile, 0..3
    const int wc = w & 3;            // N tile, 0..3
    const int l15 = lane & 15;
    const int l4  = lane >> 4;

    // ---------------- P1: count/pos loads FIRST (oldest VMEM, so counted vmcnt
    // waits on the chunk DMAs below also cover them)
    if (t < NATOM) {
        float m = mask[b * NATOM + t];
        unsigned long long bal = __ballot(m > 0.5f);
        if ((t & 63) == 0) cntBs[t >> 6] = __popcll(bal);
        const float* p = pos + ((size_t)b * NATOM + t) * 3;
        posXs[t] = p[0]; posYs[t] = p[1]; posZs[t] = p[2];
    }
    if (t < NATOM * 3) amBs[t] = 0.f;

    // ---------------- P2: kx slab -> LDS via global_load_lds (no VGPR round-trip),
    // 4 chunks x 32 rows, double-buffered; counted vmcnt + raw s_barrier keep the
    // next chunk's DMA in flight while the current chunk is activated.
    const float* slab = kx + (size_t)b * (NATOM * ROWLEN);   // 131584B, 16B-aligned

    auto issue_chunk = [&](int c) {                // 2056 16B-units per chunk
        const float* src = slab + c * 8224;        // 8224 floats
        char* dst = lds + (c & 1) * RAWSZ;
        __builtin_amdgcn_global_load_lds(GLD(src + (size_t)t * 4),
                                         LDSP(dst + (size_t)t * 16), 16, 0, 0);
        __builtin_amdgcn_global_load_lds(GLD(src + (size_t)(t + 1024) * 4),
                                         LDSP(dst + (size_t)(t + 1024) * 16), 16, 0, 0);
        if (t < 8)                                 // tail 8 units (wave 0 only)
            __builtin_amdgcn_global_load_lds(GLD(src + (size_t)(t + 2048) * 4),
                                             LDSP(dst + (size_t)(t + 2048) * 16), 16, 0, 0);
    };
    auto wait_prev = [&]() {                       // leave newest chunk in flight
        if (w == 0) asm volatile("s_waitcnt vmcnt(3)" ::: "memory");
        else        asm volatile("s_waitcnt vmcnt(2)" ::: "memory");
        SB();
    };
    auto barrier_raw = [&]() { SB(); __builtin_amdgcn_s_barrier(); SB(); };
    auto process_chunk = [&](int c) {              // raw f32 -> activations -> planes
        const float* raw = (const float*)(lds + (c & 1) * RAWSZ);
        const bool isX = (w < 8);                  // wave-uniform activation branch
        const int wl = w & 7;
        char* base = lds + (isX ? PPH : PQH);
        const int phase = isX ? 0 : 64;
        const int off = isX ? 0 : 128;
        #pragma unroll
        for (int rr = 0; rr < 4; ++rr) {
            const int rin = wl * 4 + rr;           // row in chunk
            const int row = c * 32 + rin;          // global row
            float x0 = raw[rin * 257 + off + lane];
            float x1 = raw[rin * 257 + off + lane + 64];
            float a0 = isX ? fast_ssp(x0) : fmaxf(x0, 0.f);
            float a1 = isX ? fast_ssp(x1) : fmaxf(x1, 0.f);
            *(unsigned short*)(base + swzp(row, lane * 2, phase)) = cvt1(a0);
            *(unsigned short*)(base + swzp(row, (lane + 64) * 2, phase)) = cvt1(a1);
        }
        if (!isX && lane < 4) {                    // log_std = col 256
            int rin = wl * 4 + lane;
            lsBs[c * 32 + rin] = raw[rin * 257 + 256];
        }
    };

    SB();
    issue_chunk(0);
    issue_chunk(1);
    SB();
    wait_prev();  barrier_raw();  process_chunk(0);  barrier_raw();  issue_chunk(2);
    wait_prev();  barrier_raw();  process_chunk(1);  barrier_raw();  issue_chunk(3);
    wait_prev();  barrier_raw();  process_chunk(2);  barrier_raw();
    asm volatile("s_waitcnt vmcnt(0)" ::: "memory");
    barrier_raw();
    process_chunk(3);
    __syncthreads();                 // B1: planes + count + pos ready
    const int count = cntBs[0] + cntBs[1];   // mask is a contiguous prefix

    // ---------------- P3 (merged): X and K GEMMs in one compute phase.
    const int n0 = wc * 32;                    // atom tile base (N-dim)
    const bool nact = (n0 < count);
    u16x4 xpk[2][2], kpk[2][2];
    if (nact) {
        #pragma unroll
        for (int mat = 0; mat < 2; ++mat) {
            const char* act = lds + (mat ? PQH : PPH);
            const int phase = mat ? 64 : 0;
            const unsigned short* WH = ws + mat * 32768;
            const unsigned short* WL = WH + 16384;
            const float* bias = mat ? bk : bx;
            f32x4 acc[2][2] = {};
            for (int ks = 0; ks < 4; ++ks) {
                const int e0 = ks * 32 + l4 * 8;   // k-offset for this lane
                bf16x8 wh[2], wl[2], ah[2];
                #pragma unroll
                for (int mf = 0; mf < 2; ++mf) {
                    int orow = wr * 32 + mf * 16 + l15;
                    wh[mf] = *(const bf16x8*)(WH + orow * 128 + e0);
                    wl[mf] = *(const bf16x8*)(WL + orow * 128 + e0);
                }
                #pragma unroll
                for (int nf = 0; nf < 2; ++nf) {
                    int jrow = n0 + nf * 16 + l15;
                    ah[nf] = *(const bf16x8*)(act + swzp(jrow, e0 * 2, phase));
                }
                #pragma unroll
                for (int mf = 0; mf < 2; ++mf)
                    #pragma unroll
                    for (int nf = 0; nf < 2; ++nf) {
                        acc[mf][nf] = __builtin_amdgcn_mfma_f32_16x16x32_bf16(wh[mf], ah[nf], acc[mf][nf], 0, 0, 0);
                        acc[mf][nf] = __builtin_amdgcn_mfma_f32_16x16x32_bf16(wl[mf], ah[nf], acc[mf][nf], 0, 0, 0);
                    }
            }
            #pragma unroll
            for (int mf = 0; mf < 2; ++mf) {
                int ob = wr * 32 + mf * 16 + l4 * 4;
                f32x4 b4 = *(const f32x4*)(bias + ob);
                #pragma unroll
                for (int nf = 0; nf < 2; ++nf) {
                    u16x4 hs;
                    #pragma unroll
                    for (int r = 0; r < 4; ++r) hs[r] = cvt1(acc[mf][nf][r] + b4[r]);
                    if (mat) kpk[mf][nf] = hs; else xpk[mf][nf] = hs;
                }
            }
        }
    }
    __syncthreads();                 // B2: all activation-plane reads complete
    if (nact) {
        #pragma unroll
        for (int mf = 0; mf < 2; ++mf) {
            int ob2 = (wr * 32 + mf * 16 + l4 * 4) * 2;
            #pragma unroll
            for (int nf = 0; nf < 2; ++nf) {
                int jrow = n0 + nf * 16 + l15;               // atom (D col)
                *(u16x4*)(lds + PPH + swzp(jrow, ob2, 0))  = xpk[mf][nf];
                *(u16x4*)(lds + PQH + swzp(jrow, ob2, 64)) = kpk[mf][nf];
            }
        }
    }
    __syncthreads();                 // B3: X,K planes ready

    // ---------------- P4: Grams G = X@X^T, K@K^T (bf16) + pairwise epilogue
    const int m0g = wr * 32;       // i tile base
    const int n0g = wc * 32;       // j tile base
    f32x4 gx[2][2] = {}, gk[2][2] = {};
    const bool active = (m0g < count) && (n0g < count);
    if (active) {
        for (int ks = 0; ks < 4; ++ks) {           // X gram
            const int e0b = (ks * 32 + l4 * 8) * 2;
            bf16x8 aH[2], bH[2];
            #pragma unroll
            for (int mf = 0; mf < 2; ++mf)
                aH[mf] = *(const bf16x8*)(lds + PPH + swzp(m0g + mf * 16 + l15, e0b, 0));
            #pragma unroll
            for (int nf = 0; nf < 2; ++nf)
                bH[nf] = *(const bf16x8*)(lds + PPH + swzp(n0g + nf * 16 + l15, e0b, 0));
            #pragma unroll
            for (int mf = 0; mf < 2; ++mf)
                #pragma unroll
                for (int nf = 0; nf < 2; ++nf)
                    gx[mf][nf] = __builtin_amdgcn_mfma_f32_16x16x32_bf16(aH[mf], bH[nf], gx[mf][nf], 0, 0, 0);
        }
        for (int ks = 0; ks < 4; ++ks) {           // K gram
            const int e0b = (ks * 32 + l4 * 8) * 2;
            bf16x8 aH[2], bH[2];
            #pragma unroll
            for (int mf = 0; mf < 2; ++mf)
                aH[mf] = *(const bf16x8*)(lds + PQH + swzp(m0g + mf * 16 + l15, e0b, 64));
            #pragma unroll
            for (int nf = 0; nf < 2; ++nf)
                bH[nf] = *(const bf16x8*)(lds + PQH + swzp(n0g + nf * 16 + l15, e0b, 64));
            #pragma unroll
            for (int mf = 0; mf < 2; ++mf)
                #pragma unroll
                for (int nf = 0; nf < 2; ++nf)
                    gk[mf][nf] = __builtin_amdgcn_mfma_f32_16x16x32_bf16(aH[mf], bH[nf], gk[mf][nf], 0, 0, 0);
        }
        // pairwise epilogue on D-frags: lane's column j fixed per nf
        const float inv_e = 0.08838834764831845f;            // 1/sqrt(128)
        #pragma unroll
        for (int nf = 0; nf < 2; ++nf) {
            const int j = n0g + nf * 16 + l15;
            const bool jvalid = (j < count);
            const float pjx = posXs[j], pjy = posYs[j], pjz = posZs[j];
            float amx = 0.f, amy = 0.f, amz = 0.f;
            #pragma unroll
            for (int mf = 0; mf < 2; ++mf) {
                #pragma unroll
                for (int r = 0; r < 4; ++r) {
                    const int i = m0g + mf * 16 + l4 * 4 + r;
                    float dx = pjx - posXs[i];
                    float dy = pjy - posYs[i];
                    float dz = pjz - posZs[i];
                    float r2 = fmaf(dx, dx, fmaf(dy, dy, dz * dz)) + 1e-16f;
                    float rr = sqrtf(r2);
                    bool ok = jvalid && (i < count) && (rr < 5.0f);
                    float fc = ok ? (0.5f * (__cosf(rr * 0.62831853071795865f) + 1.f)) : 0.f;
                    float xs = fmaf(gx[mf][nf][r], -0.044194173824159216f, rr * 0.5f);
                    float fv = xs * (gk[mf][nf][r] * inv_e) * fc;
                    float wgt = fv / (rr + 1e-8f);
                    amx = fmaf(dx, wgt, amx);
                    amy = fmaf(dy, wgt, amy);
                    amz = fmaf(dz, wgt, amz);
                }
            }
            amx += __shfl_xor(amx, 16); amx += __shfl_xor(amx, 32);
            amy += __shfl_xor(amy, 16); amy += __shfl_xor(amy, 32);
            amz += __shfl_xor(amz, 16); amz += __shfl_xor(amz, 32);
            if (l4 == 0 && jvalid) {
                atomicAdd(&amBs[j * 3 + 0], amx);
                atomicAdd(&amBs[j * 3 + 1], amy);
                atomicAdd(&amBs[j * 3 + 2], amz);
            }
        }
    }
    __syncthreads();                 // B4: actions_mean complete

    // ---------------- P5: outputs
    if (t < 96) {
        f32x4 ev4 = *(const f32x4*)(evala + (size_t)b * 384 + t * 4);
        f32x4 o4;
        #pragma unroll
        for (int c = 0; c < 4; ++c) {
            int atom = (t * 4 + c) / 3;
            o4[c] = (atom < count) ? ev4[c] : 0.f;
        }
        *(f32x4*)(out + (size_t)b * 384 + t * 4) = o4;
    }
    float lp = 0.f;
    if (t < NATOM && t < count) {
        const float* ev = evala + ((size_t)b * NATOM + t) * 3;
        float e0v = ev[0], e1v = ev[1], e2v = ev[2];
        float scale = scale_ptr[0];
        float ax = amBs[t * 3 + 0], ay = amBs[t * 3 + 1], az = amBs[t * 3 + 2];
        float nrm = sqrtf(fmaf(ax, ax, fmaf(ay, ay, az * az)) + 1e-16f) + 1e-8f;
        float qe = __expf(-2.f * nrm);
        float th = (1.f - qe) / (1.f + qe);
        float sc = th / nrm * scale;
        float ls = fminf(fmaxf(lsBs[t], -20.f), 2.f);
        float sig = __expf(ls) * scale;
        float sinv = 1.f / sig;
        float zx = (e0v - ax * sc) * sinv;
        float zy = (e1v - ay * sc) * sinv;
        float zz = (e2v - az * sc) * sinv;
        lp = -0.5f * (zx * zx + zy * zy + zz * zz) - 3.f * __logf(sig)
             - 3.f * 0.91893853320467274f;
    }
    #pragma unroll
    for (int off = 32; off > 0; off >>= 1) lp += __shfl_down(lp, off);
    if (t == 0)  redBs[0] = lp;
    if (t == 64) redBs[1] = lp;
    __syncthreads();                 // B5
    if (t == 0) out[(size_t)NBATCH * NATOM * 3 + b] = redBs[0] + redBs[1];
}

extern "C" void kernel_launch(void* const* d_in, const int* in_sizes, int n_in,
                              void* d_out, int out_size, void* d_ws, size_t ws_size,
                              hipStream_t stream) {
    const float* kx    = (const float*)d_in[0];
    const float* pos   = (const float*)d_in[1];
    const float* mask  = (const float*)d_in[2];
    const float* scale = (const float*)d_in[3];
    const float* ev    = (const float*)d_in[4];
    const float* Wx    = (const float*)d_in[5];
    const float* bx    = (const float*)d_in[6];
    const float* Wk    = (const float*)d_in[7];
    const float* bk    = (const float*)d_in[8];
    float* out = (float*)d_out;
    unsigned short* ws = (unsigned short*)d_ws;

    // W hi/lo split (128KB in d_ws), recomputed each launch (deterministic)
    hipLaunchKernelGGL(wsplit_kernel, dim3(128), dim3(256), 0, stream, Wx, Wk, ws);

    (void)hipFuncSetAttribute((const void*)gen_actions_kernel,
                              hipFuncAttributeMaxDynamicSharedMemorySize,
                              LDS_TOTAL);
    hipLaunchKernelGGL(gen_actions_kernel, dim3(NBATCH), dim3(THREADS), LDS_TOTAL, stream,
                       kx, pos, mask, scale, ev, bx, bk, ws, out);
}

// Round 10
// 54.757 us; speedup vs baseline: 1.3727x; 1.3727x over previous
//
#include <hip/hip_runtime.h>
#include <math.h>

#define EDIM 128
#define NATOM 128
#define NBATCH 512
#define THREADS 1024
#define ROWLEN 257

typedef __attribute__((ext_vector_type(8))) short bf16x8;           // 8 bf16 (4 VGPRs)
typedef __attribute__((ext_vector_type(4))) float f32x4;            // MFMA C/D frag
typedef __attribute__((ext_vector_type(4))) unsigned short u16x4;   // 8B packed bf16

__device__ __forceinline__ unsigned short f2bf(float f) {       // RNE float->bf16
    unsigned u = __float_as_uint(f);
    u += 0x7FFFu + ((u >> 16) & 1u);
    return (unsigned short)(u >> 16);
}
// 1-op RNE f32->bf16 via HW pack convert (src0==src1 -> order-immune)
__device__ __forceinline__ unsigned short cvt1(float x) {
    unsigned r;
    asm("v_cvt_pk_bf16_f32 %0, %1, %1" : "=v"(r) : "v"(x));
    return (unsigned short)r;
}
__device__ __forceinline__ float fast_ssp(float x) {            // softplus(x)-log2, stable
    return fmaxf(x, 0.f) + __logf(1.f + __expf(-fabsf(x))) - 0.69314718055994531f;
}
// XOR swizzle on a row-major [128][256B] bf16 plane; phase decorrelates X vs K plane.
__device__ __forceinline__ int swzp(int row, int cbyte, int phase) {
    return row * 256 + ((cbyte ^ phase) ^ ((row & 7) << 4));
}

#define PH 0
#define QH 32768

// W -> bf16 (plain RNE; accuracy margin covers the dropped lo-term: R4-R9 absmax 4.0 / thr 76.5)
__global__ void wcvt_kernel(const float* __restrict__ Wx,
                            const float* __restrict__ Wk,
                            unsigned short* __restrict__ ws) {
    int g = blockIdx.x * 256 + threadIdx.x;          // 0..32767
    const float* src = (g < 16384) ? Wx : Wk;
    ws[g] = f2bf(src[g & 16383]);
}

__global__ void __launch_bounds__(THREADS, 8)   // cap 64 regs/wave -> 2 blocks/CU resident
gen_actions_kernel(const float* __restrict__ kx,
                   const float* __restrict__ pos,
                   const float* __restrict__ mask,
                   const float* __restrict__ scale_ptr,
                   const float* __restrict__ evala,
                   const float* __restrict__ bx,
                   const float* __restrict__ bk,
                   const unsigned short* __restrict__ ws,
                   float* __restrict__ out)
{
    extern __shared__ char lds[];        // act_x/X plane (32KB) + act_k/K plane (32KB)
    __shared__ float posXs[NATOM], posYs[NATOM], posZs[NATOM], lsBs[NATOM];
    __shared__ float amBs[NATOM * 3];
    __shared__ float redBs[2];
    __shared__ int   cntBs[2];

    const int b = blockIdx.x;
    const int t = threadIdx.x;
    const int lane = t & 63;
    const int w = t >> 6;            // wave 0..15
    const int wr = w >> 2;           // M tile (features / atoms-i), 0..3
    const int wc = w & 3;            // N tile (atoms-j), 0..3
    const int l15 = lane & 15;
    const int l4  = lane >> 4;

    // ---------------- P1: count, positions, log_std, zero accumulators
    if (t < NATOM) {
        float m = mask[b * NATOM + t];
        unsigned long long bal = __ballot(m > 0.5f);
        if ((t & 63) == 0) cntBs[t >> 6] = __popcll(bal);
        const float* p = pos + ((size_t)b * NATOM + t) * 3;
        posXs[t] = p[0]; posYs[t] = p[1]; posZs[t] = p[2];
        lsBs[t] = kx[(size_t)b * (NATOM * ROWLEN) + t * ROWLEN + 2 * EDIM];
    }
    if (t < NATOM * 3) amBs[t] = 0.f;

    // ---------------- P2: coalesced kx stream -> bf16 activation planes.
    // Wave = one half-row (128 floats): lane reads scalars at row*1028B + (lane, lane+64)*4B
    // -> every load instruction covers a 256B contiguous segment. j<8 waves: softplus
    // halves (cols 0..127); j>=8: relu halves (cols 128..255) — wave-uniform branch.
    // No masking: masked-row garbage is killed downstream (guards/count gates).
    {
        const float* kb = kx + (size_t)b * (NATOM * ROWLEN);
        #pragma unroll
        for (int j = 0; j < 16; ++j) {
            const int row = (j * 16 + w) & 127;
            const bool isX = (j < 8);
            const float* src = kb + row * ROWLEN + (isX ? 0 : 128);
            float x0 = src[lane];
            float x1 = src[lane + 64];
            float a0 = isX ? fast_ssp(x0) : fmaxf(x0, 0.f);
            float a1 = isX ? fast_ssp(x1) : fmaxf(x1, 0.f);
            char* base = lds + (isX ? PH : QH);
            const int phase = isX ? 0 : 64;
            *(unsigned short*)(base + swzp(row, lane * 2, phase)) = cvt1(a0);
            *(unsigned short*)(base + swzp(row, (lane + 64) * 2, phase)) = cvt1(a1);
        }
    }
    __syncthreads();                 // B1: planes + count + pos ready
    const int count = cntBs[0] + cntBs[1];   // mask is a contiguous prefix

    // ---------------- P3 (merged): X and K GEMMs in one compute phase (bf16 W).
    const int n0 = wc * 32;                    // atom tile base (N-dim)
    const bool nact = (n0 < count);
    u16x4 xpk[2][2], kpk[2][2];
    if (nact) {
        #pragma unroll
        for (int mat = 0; mat < 2; ++mat) {
            const char* act = lds + (mat ? QH : PH);
            const int phase = mat ? 64 : 0;
            const unsigned short* WH = ws + mat * 16384;
            const float* bias = mat ? bk : bx;
            f32x4 acc[2][2] = {};
            for (int ks = 0; ks < 4; ++ks) {
                const int e0 = ks * 32 + l4 * 8;   // k-offset for this lane
                bf16x8 wh[2], ah[2];
                #pragma unroll
                for (int mf = 0; mf < 2; ++mf) {
                    int orow = wr * 32 + mf * 16 + l15;
                    wh[mf] = *(const bf16x8*)(WH + orow * 128 + e0);
                }
                #pragma unroll
                for (int nf = 0; nf < 2; ++nf) {
                    int jrow = n0 + nf * 16 + l15;
                    ah[nf] = *(const bf16x8*)(act + swzp(jrow, e0 * 2, phase));
                }
                #pragma unroll
                for (int mf = 0; mf < 2; ++mf)
                    #pragma unroll
                    for (int nf = 0; nf < 2; ++nf)
                        acc[mf][nf] = __builtin_amdgcn_mfma_f32_16x16x32_bf16(wh[mf], ah[nf], acc[mf][nf], 0, 0, 0);
            }
            #pragma unroll
            for (int mf = 0; mf < 2; ++mf) {
                int ob = wr * 32 + mf * 16 + l4 * 4;
                f32x4 b4 = *(const f32x4*)(bias + ob);
                #pragma unroll
                for (int nf = 0; nf < 2; ++nf) {
                    u16x4 hs;
                    #pragma unroll
                    for (int r = 0; r < 4; ++r) hs[r] = cvt1(acc[mf][nf][r] + b4[r]);
                    if (mat) kpk[mf][nf] = hs; else xpk[mf][nf] = hs;
                }
            }
        }
    }
    __syncthreads();                 // B2: all activation-plane reads complete
    if (nact) {
        #pragma unroll
        for (int mf = 0; mf < 2; ++mf) {
            int ob2 = (wr * 32 + mf * 16 + l4 * 4) * 2;
            #pragma unroll
            for (int nf = 0; nf < 2; ++nf) {
                int jrow = n0 + nf * 16 + l15;               // atom (D col)
                *(u16x4*)(lds + PH + swzp(jrow, ob2, 0))  = xpk[mf][nf];
                *(u16x4*)(lds + QH + swzp(jrow, ob2, 64)) = kpk[mf][nf];
            }
        }
    }
    __syncthreads();                 // B3: X,K planes ready

    // ---------------- P4: Grams G = X@X^T, K@K^T (bf16) + pairwise epilogue
    const int m0g = wr * 32;       // i tile base
    const int n0g = wc * 32;       // j tile base
    f32x4 gx[2][2] = {}, gk[2][2] = {};
    const bool active = (m0g < count) && (n0g < count);
    if (active) {
        for (int ks = 0; ks < 4; ++ks) {           // X gram
            const int e0b = (ks * 32 + l4 * 8) * 2;
            bf16x8 aH[2], bH[2];
            #pragma unroll
            for (int mf = 0; mf < 2; ++mf)
                aH[mf] = *(const bf16x8*)(lds + PH + swzp(m0g + mf * 16 + l15, e0b, 0));
            #pragma unroll
            for (int nf = 0; nf < 2; ++nf)
                bH[nf] = *(const bf16x8*)(lds + PH + swzp(n0g + nf * 16 + l15, e0b, 0));
            #pragma unroll
            for (int mf = 0; mf < 2; ++mf)
                #pragma unroll
                for (int nf = 0; nf < 2; ++nf)
                    gx[mf][nf] = __builtin_amdgcn_mfma_f32_16x16x32_bf16(aH[mf], bH[nf], gx[mf][nf], 0, 0, 0);
        }
        for (int ks = 0; ks < 4; ++ks) {           // K gram
            const int e0b = (ks * 32 + l4 * 8) * 2;
            bf16x8 aH[2], bH[2];
            #pragma unroll
            for (int mf = 0; mf < 2; ++mf)
                aH[mf] = *(const bf16x8*)(lds + QH + swzp(m0g + mf * 16 + l15, e0b, 64));
            #pragma unroll
            for (int nf = 0; nf < 2; ++nf)
                bH[nf] = *(const bf16x8*)(lds + QH + swzp(n0g + nf * 16 + l15, e0b, 64));
            #pragma unroll
            for (int mf = 0; mf < 2; ++mf)
                #pragma unroll
                for (int nf = 0; nf < 2; ++nf)
                    gk[mf][nf] = __builtin_amdgcn_mfma_f32_16x16x32_bf16(aH[mf], bH[nf], gk[mf][nf], 0, 0, 0);
        }
        // pairwise epilogue on D-frags: lane's column j fixed per nf
        const float inv_e = 0.08838834764831845f;            // 1/sqrt(128)
        #pragma unroll
        for (int nf = 0; nf < 2; ++nf) {
            const int j = n0g + nf * 16 + l15;
            const bool jvalid = (j < count);
            const float pjx = posXs[j], pjy = posYs[j], pjz = posZs[j];
            float amx = 0.f, amy = 0.f, amz = 0.f;
            #pragma unroll
            for (int mf = 0; mf < 2; ++mf) {
                #pragma unroll
                for (int r = 0; r < 4; ++r) {
                    const int i = m0g + mf * 16 + l4 * 4 + r;
                    float dx = pjx - posXs[i];
                    float dy = pjy - posYs[i];
                    float dz = pjz - posZs[i];
                    float r2 = fmaf(dx, dx, fmaf(dy, dy, dz * dz)) + 1e-16f;
                    float rr = sqrtf(r2);
                    bool ok = jvalid && (i < count) && (rr < 5.0f);
                    float fc = ok ? (0.5f * (__cosf(rr * 0.62831853071795865f) + 1.f)) : 0.f;
                    float xs = fmaf(gx[mf][nf][r], -0.044194173824159216f, rr * 0.5f);
                    float fv = xs * (gk[mf][nf][r] * inv_e) * fc;
                    float wgt = fv / (rr + 1e-8f);
                    amx = fmaf(dx, wgt, amx);
                    amy = fmaf(dy, wgt, amy);
                    amz = fmaf(dz, wgt, amz);
                }
            }
            amx += __shfl_xor(amx, 16); amx += __shfl_xor(amx, 32);
            amy += __shfl_xor(amy, 16); amy += __shfl_xor(amy, 32);
            amz += __shfl_xor(amz, 16); amz += __shfl_xor(amz, 32);
            if (l4 == 0 && jvalid) {
                atomicAdd(&amBs[j * 3 + 0], amx);
                atomicAdd(&amBs[j * 3 + 1], amy);
                atomicAdd(&amBs[j * 3 + 2], amz);
            }
        }
    }
    __syncthreads();                 // B4: actions_mean complete

    // ---------------- P5: outputs
    if (t < 96) {
        f32x4 ev4 = *(const f32x4*)(evala + (size_t)b * 384 + t * 4);
        f32x4 o4;
        #pragma unroll
        for (int c = 0; c < 4; ++c) {
            int atom = (t * 4 + c) / 3;
            o4[c] = (atom < count) ? ev4[c] : 0.f;
        }
        *(f32x4*)(out + (size_t)b * 384 + t * 4) = o4;
    }
    float lp = 0.f;
    if (t < NATOM && t < count) {
        const float* ev = evala + ((size_t)b * NATOM + t) * 3;
        float e0v = ev[0], e1v = ev[1], e2v = ev[2];
        float scale = scale_ptr[0];
        float ax = amBs[t * 3 + 0], ay = amBs[t * 3 + 1], az = amBs[t * 3 + 2];
        float nrm = sqrtf(fmaf(ax, ax, fmaf(ay, ay, az * az)) + 1e-16f) + 1e-8f;
        float qe = __expf(-2.f * nrm);
        float th = (1.f - qe) / (1.f + qe);
        float sc = th / nrm * scale;
        float ls = fminf(fmaxf(lsBs[t], -20.f), 2.f);
        float sig = __expf(ls) * scale;
        float sinv = 1.f / sig;
        float zx = (e0v - ax * sc) * sinv;
        float zy = (e1v - ay * sc) * sinv;
        float zz = (e2v - az * sc) * sinv;
        lp = -0.5f * (zx * zx + zy * zy + zz * zz) - 3.f * __logf(sig)
             - 3.f * 0.91893853320467274f;
    }
    #pragma unroll
    for (int off = 32; off > 0; off >>= 1) lp += __shfl_down(lp, off);
    if (t == 0)  redBs[0] = lp;
    if (t == 64) redBs[1] = lp;
    __syncthreads();                 // B5
    if (t == 0) out[(size_t)NBATCH * NATOM * 3 + b] = redBs[0] + redBs[1];
}

extern "C" void kernel_launch(void* const* d_in, const int* in_sizes, int n_in,
                              void* d_out, int out_size, void* d_ws, size_t ws_size,
                              hipStream_t stream) {
    const float* kx    = (const float*)d_in[0];
    const float* pos   = (const float*)d_in[1];
    const float* mask  = (const float*)d_in[2];
    const float* scale = (const float*)d_in[3];
    const float* ev    = (const float*)d_in[4];
    const float* Wx    = (const float*)d_in[5];
    const float* bx    = (const float*)d_in[6];
    const float* Wk    = (const float*)d_in[7];
    const float* bk    = (const float*)d_in[8];
    float* out = (float*)d_out;
    unsigned short* ws = (unsigned short*)d_ws;

    // W -> bf16 (64KB in d_ws), recomputed each launch (deterministic)
    hipLaunchKernelGGL(wcvt_kernel, dim3(128), dim3(256), 0, stream, Wx, Wk, ws);

    const size_t shbytes = 65536;   // 2 planes x 32KB dynamic LDS
    (void)hipFuncSetAttribute((const void*)gen_actions_kernel,
                              hipFuncAttributeMaxDynamicSharedMemorySize,
                              (int)shbytes);
    hipLaunchKernelGGL(gen_actions_kernel, dim3(NBATCH), dim3(THREADS), shbytes, stream,
                       kx, pos, mask, scale, ev, bx, bk, ws, out);
}

// Round 11
// 53.091 us; speedup vs baseline: 1.4158x; 1.0314x over previous
//
#include <hip/hip_runtime.h>
#include <math.h>

#define EDIM 128
#define NATOM 128
#define NBATCH 512
#define THREADS 512
#define ROWLEN 257

typedef __attribute__((ext_vector_type(8))) short bf16x8;           // 8 bf16 (4 VGPRs)
typedef __attribute__((ext_vector_type(4))) float f32x4;            // MFMA C/D frag
typedef __attribute__((ext_vector_type(4))) unsigned short u16x4;   // 8B packed bf16

__device__ __forceinline__ unsigned short f2bf(float f) {       // RNE float->bf16
    unsigned u = __float_as_uint(f);
    u += 0x7FFFu + ((u >> 16) & 1u);
    return (unsigned short)(u >> 16);
}
// 1-op RNE f32->bf16 via HW pack convert (src0==src1 -> order-immune)
__device__ __forceinline__ unsigned short cvt1(float x) {
    unsigned r;
    asm("v_cvt_pk_bf16_f32 %0, %1, %1" : "=v"(r) : "v"(x));
    return (unsigned short)r;
}
__device__ __forceinline__ float fast_ssp(float x) {            // softplus(x)-log2, stable
    return fmaxf(x, 0.f) + __logf(1.f + __expf(-fabsf(x))) - 0.69314718055994531f;
}
// XOR swizzle on a row-major [128][256B] bf16 plane; phase decorrelates X vs K plane.
__device__ __forceinline__ int swzp(int row, int cbyte, int phase) {
    return row * 256 + ((cbyte ^ phase) ^ ((row & 7) << 4));
}

#define PH 0
#define QH 32768

// W -> bf16 (plain RNE; accuracy margin covers dropped lo-term: absmax 4.0 / thr 76.5)
__global__ void wcvt_kernel(const float* __restrict__ Wx,
                            const float* __restrict__ Wk,
                            unsigned short* __restrict__ ws) {
    int g = blockIdx.x * 256 + threadIdx.x;          // 0..32767
    const float* src = (g < 16384) ? Wx : Wk;
    ws[g] = f2bf(src[g & 16383]);
}

__global__ void __launch_bounds__(THREADS, 4)   // 4 waves/EU -> 2 blocks/CU, VGPR cap 128
gen_actions_kernel(const float* __restrict__ kx,
                   const float* __restrict__ pos,
                   const float* __restrict__ mask,
                   const float* __restrict__ scale_ptr,
                   const float* __restrict__ evala,
                   const float* __restrict__ bx,
                   const float* __restrict__ bk,
                   const unsigned short* __restrict__ ws,
                   float* __restrict__ out)
{
    extern __shared__ char lds[];        // act_x/X plane (32KB) + act_k/K plane (32KB)
    __shared__ float posXs[NATOM], posYs[NATOM], posZs[NATOM], lsBs[NATOM];
    __shared__ float amBs[NATOM * 3];
    __shared__ float redBs[2];
    __shared__ int   cntBs[2];

    const int b = blockIdx.x;
    const int t = threadIdx.x;
    const int lane = t & 63;
    const int w = t >> 6;            // wave 0..7
    const int wrb = w >> 2;          // M tile base: this wave owns tiles wrb, wrb+2
    const int wc = w & 3;            // N tile (atoms-j), 0..3
    const int l15 = lane & 15;
    const int l4  = lane >> 4;

    // ---------------- P1: count, positions, log_std, zero accumulators
    if (t < NATOM) {
        float m = mask[b * NATOM + t];
        unsigned long long bal = __ballot(m > 0.5f);
        if ((t & 63) == 0) cntBs[t >> 6] = __popcll(bal);
        const float* p = pos + ((size_t)b * NATOM + t) * 3;
        posXs[t] = p[0]; posYs[t] = p[1]; posZs[t] = p[2];
        lsBs[t] = kx[(size_t)b * (NATOM * ROWLEN) + t * ROWLEN + 2 * EDIM];
    }
    if (t < NATOM * 3) amBs[t] = 0.f;

    // ---------------- P2: coalesced kx stream -> bf16 activation planes.
    // Wave = one half-row (128 floats) per iter: lane reads scalars at
    // row*1028B + (lane, lane+64)*4B -> each load instr covers a 256B contiguous
    // segment. j<16: softplus halves (cols 0..127); j>=16: relu halves. The isX
    // branch is wave-uniform (depends only on j). No masking: masked-row garbage
    // is killed downstream (guards/count gates).
    {
        const float* kb = kx + (size_t)b * (NATOM * ROWLEN);
        #pragma unroll 4
        for (int j = 0; j < 32; ++j) {
            const int row = (j * 8 + w) & 127;
            const bool isX = (j < 16);
            const float* src = kb + row * ROWLEN + (isX ? 0 : 128);
            float x0 = src[lane];
            float x1 = src[lane + 64];
            float a0 = isX ? fast_ssp(x0) : fmaxf(x0, 0.f);
            float a1 = isX ? fast_ssp(x1) : fmaxf(x1, 0.f);
            char* base = lds + (isX ? PH : QH);
            const int phase = isX ? 0 : 64;
            *(unsigned short*)(base + swzp(row, lane * 2, phase)) = cvt1(a0);
            *(unsigned short*)(base + swzp(row, (lane + 64) * 2, phase)) = cvt1(a1);
        }
    }
    __syncthreads();                 // B1: planes + count + pos ready
    const int count = cntBs[0] + cntBs[1];   // mask is a contiguous prefix

    const int n0 = wc * 32;          // atom tile base (N-dim), shared by both p-tiles
    const bool nact = (n0 < count);

    // ---------------- P3: X then K GEMM (bf16 W), per-mat write-back to cut
    // cross-barrier register state to 16 regs; mat1 MFMAs overlap X-write drain.
    #define GEMM_MAT(MAT, PLANE, PHASE, WSOFF, BIAS)                                    \
    {                                                                                   \
        u16x4 pk[2][2][2];                                                              \
        if (nact) {                                                                     \
            const char* act = lds + PLANE;                                              \
            const unsigned short* WH = ws + WSOFF;                                      \
            f32x4 acc[2][2][2] = {};                                                    \
            for (int ks = 0; ks < 4; ++ks) {                                            \
                const int e0 = ks * 32 + l4 * 8;                                        \
                bf16x8 ah[2];                                                           \
                _Pragma("unroll")                                                       \
                for (int nf = 0; nf < 2; ++nf)                                          \
                    ah[nf] = *(const bf16x8*)(act + swzp(n0 + nf * 16 + l15, e0 * 2, PHASE)); \
                _Pragma("unroll")                                                       \
                for (int p = 0; p < 2; ++p) {                                           \
                    _Pragma("unroll")                                                   \
                    for (int mf = 0; mf < 2; ++mf) {                                    \
                        int orow = (wrb + 2 * p) * 32 + mf * 16 + l15;                  \
                        bf16x8 wh = *(const bf16x8*)(WH + orow * 128 + e0);             \
                        _Pragma("unroll")                                               \
                        for (int nf = 0; nf < 2; ++nf)                                  \
                            acc[p][mf][nf] = __builtin_amdgcn_mfma_f32_16x16x32_bf16(wh, ah[nf], acc[p][mf][nf], 0, 0, 0); \
                    }                                                                   \
                }                                                                       \
            }                                                                           \
            _Pragma("unroll")                                                           \
            for (int p = 0; p < 2; ++p)                                                 \
                _Pragma("unroll")                                                       \
                for (int mf = 0; mf < 2; ++mf) {                                        \
                    int ob = (wrb + 2 * p) * 32 + mf * 16 + l4 * 4;                     \
                    f32x4 b4 = *(const f32x4*)(BIAS + ob);                              \
                    _Pragma("unroll")                                                   \
                    for (int nf = 0; nf < 2; ++nf) {                                    \
                        u16x4 hs;                                                       \
                        _Pragma("unroll")                                               \
                        for (int r = 0; r < 4; ++r) hs[r] = cvt1(acc[p][mf][nf][r] + b4[r]); \
                        pk[p][mf][nf] = hs;                                             \
                    }                                                                   \
                }                                                                       \
        }                                                                               \
        __syncthreads();   /* all reads of this act plane complete */                   \
        if (nact) {                                                                     \
            _Pragma("unroll")                                                           \
            for (int p = 0; p < 2; ++p)                                                 \
                _Pragma("unroll")                                                       \
                for (int mf = 0; mf < 2; ++mf) {                                        \
                    int ob2 = ((wrb + 2 * p) * 32 + mf * 16 + l4 * 4) * 2;              \
                    _Pragma("unroll")                                                   \
                    for (int nf = 0; nf < 2; ++nf) {                                    \
                        int jrow = n0 + nf * 16 + l15;                                  \
                        *(u16x4*)(lds + PLANE + swzp(jrow, ob2, PHASE)) = pk[p][mf][nf]; \
                    }                                                                   \
                }                                                                       \
        }                                                                               \
    }

    GEMM_MAT(0, PH, 0,  0,     bx)      // B2a inside; X written to PH
    GEMM_MAT(1, QH, 64, 16384, bk)      // B2b inside; K written to QH
    __syncthreads();                 // B3: X,K planes ready

    // ---------------- P4: Grams G = X@X^T, K@K^T (bf16) + pairwise epilogue
    const int n0g = n0;
    if (n0g < count) {
        f32x4 gx[2][2][2] = {}, gk[2][2][2] = {};
        for (int ks = 0; ks < 4; ++ks) {           // both grams, B-frags shared across p
            const int e0b = (ks * 32 + l4 * 8) * 2;
            bf16x8 bX[2], bK[2];
            #pragma unroll
            for (int nf = 0; nf < 2; ++nf) {
                bX[nf] = *(const bf16x8*)(lds + PH + swzp(n0g + nf * 16 + l15, e0b, 0));
                bK[nf] = *(const bf16x8*)(lds + QH + swzp(n0g + nf * 16 + l15, e0b, 64));
            }
            #pragma unroll
            for (int p = 0; p < 2; ++p) {
                const int m0g = (wrb + 2 * p) * 32;
                if (m0g < count) {
                    #pragma unroll
                    for (int mf = 0; mf < 2; ++mf) {
                        int irow = m0g + mf * 16 + l15;
                        bf16x8 aX = *(const bf16x8*)(lds + PH + swzp(irow, e0b, 0));
                        bf16x8 aK = *(const bf16x8*)(lds + QH + swzp(irow, e0b, 64));
                        #pragma unroll
                        for (int nf = 0; nf < 2; ++nf) {
                            gx[p][mf][nf] = __builtin_amdgcn_mfma_f32_16x16x32_bf16(aX, bX[nf], gx[p][mf][nf], 0, 0, 0);
                            gk[p][mf][nf] = __builtin_amdgcn_mfma_f32_16x16x32_bf16(aK, bK[nf], gk[p][mf][nf], 0, 0, 0);
                        }
                    }
                }
            }
        }
        // pairwise epilogue on D-frags: lane's column j fixed per nf; accumulate
        // over both p-tiles before one shuffle-reduce per nf.
        const float inv_e = 0.08838834764831845f;            // 1/sqrt(128)
        #pragma unroll
        for (int nf = 0; nf < 2; ++nf) {
            const int j = n0g + nf * 16 + l15;
            const bool jvalid = (j < count);
            const float pjx = posXs[j], pjy = posYs[j], pjz = posZs[j];
            float amx = 0.f, amy = 0.f, amz = 0.f;
            #pragma unroll
            for (int p = 0; p < 2; ++p) {
                const int m0g = (wrb + 2 * p) * 32;
                if (m0g < count) {
                    #pragma unroll
                    for (int mf = 0; mf < 2; ++mf) {
                        #pragma unroll
                        for (int r = 0; r < 4; ++r) {
                            const int i = m0g + mf * 16 + l4 * 4 + r;
                            float dx = pjx - posXs[i];
                            float dy = pjy - posYs[i];
                            float dz = pjz - posZs[i];
                            float r2 = fmaf(dx, dx, fmaf(dy, dy, dz * dz)) + 1e-16f;
                            float rr = sqrtf(r2);
                            bool ok = jvalid && (i < count) && (rr < 5.0f);
                            float fc = ok ? (0.5f * (__cosf(rr * 0.62831853071795865f) + 1.f)) : 0.f;
                            float xs = fmaf(gx[p][mf][nf][r], -0.044194173824159216f, rr * 0.5f);
                            float fv = xs * (gk[p][mf][nf][r] * inv_e) * fc;
                            float wgt = fv / (rr + 1e-8f);
                            amx = fmaf(dx, wgt, amx);
                            amy = fmaf(dy, wgt, amy);
                            amz = fmaf(dz, wgt, amz);
                        }
                    }
                }
            }
            amx += __shfl_xor(amx, 16); amx += __shfl_xor(amx, 32);
            amy += __shfl_xor(amy, 16); amy += __shfl_xor(amy, 32);
            amz += __shfl_xor(amz, 16); amz += __shfl_xor(amz, 32);
            if (l4 == 0 && jvalid) {
                atomicAdd(&amBs[j * 3 + 0], amx);
                atomicAdd(&amBs[j * 3 + 1], amy);
                atomicAdd(&amBs[j * 3 + 2], amz);
            }
        }
    }
    __syncthreads();                 // B4: actions_mean complete

    // ---------------- P5: outputs
    if (t < 96) {
        f32x4 ev4 = *(const f32x4*)(evala + (size_t)b * 384 + t * 4);
        f32x4 o4;
        #pragma unroll
        for (int c = 0; c < 4; ++c) {
            int atom = (t * 4 + c) / 3;
            o4[c] = (atom < count) ? ev4[c] : 0.f;
        }
        *(f32x4*)(out + (size_t)b * 384 + t * 4) = o4;
    }
    float lp = 0.f;
    if (t < NATOM && t < count) {
        const float* ev = evala + ((size_t)b * NATOM + t) * 3;
        float e0v = ev[0], e1v = ev[1], e2v = ev[2];
        float scale = scale_ptr[0];
        float ax = amBs[t * 3 + 0], ay = amBs[t * 3 + 1], az = amBs[t * 3 + 2];
        float nrm = sqrtf(fmaf(ax, ax, fmaf(ay, ay, az * az)) + 1e-16f) + 1e-8f;
        float qe = __expf(-2.f * nrm);
        float th = (1.f - qe) / (1.f + qe);
        float sc = th / nrm * scale;
        float ls = fminf(fmaxf(lsBs[t], -20.f), 2.f);
        float sig = __expf(ls) * scale;
        float sinv = 1.f / sig;
        float zx = (e0v - ax * sc) * sinv;
        float zy = (e1v - ay * sc) * sinv;
        float zz = (e2v - az * sc) * sinv;
        lp = -0.5f * (zx * zx + zy * zy + zz * zz) - 3.f * __logf(sig)
             - 3.f * 0.91893853320467274f;
    }
    #pragma unroll
    for (int off = 32; off > 0; off >>= 1) lp += __shfl_down(lp, off);
    if (t == 0)  redBs[0] = lp;
    if (t == 64) redBs[1] = lp;
    __syncthreads();                 // B5
    if (t == 0) out[(size_t)NBATCH * NATOM * 3 + b] = redBs[0] + redBs[1];
}

extern "C" void kernel_launch(void* const* d_in, const int* in_sizes, int n_in,
                              void* d_out, int out_size, void* d_ws, size_t ws_size,
                              hipStream_t stream) {
    const float* kx    = (const float*)d_in[0];
    const float* pos   = (const float*)d_in[1];
    const float* mask  = (const float*)d_in[2];
    const float* scale = (const float*)d_in[3];
    const float* ev    = (const float*)d_in[4];
    const float* Wx    = (const float*)d_in[5];
    const float* bx    = (const float*)d_in[6];
    const float* Wk    = (const float*)d_in[7];
    const float* bk    = (const float*)d_in[8];
    float* out = (float*)d_out;
    unsigned short* ws = (unsigned short*)d_ws;

    // W -> bf16 (64KB in d_ws), recomputed each launch (deterministic)
    hipLaunchKernelGGL(wcvt_kernel, dim3(128), dim3(256), 0, stream, Wx, Wk, ws);

    const size_t shbytes = 65536;   // 2 planes x 32KB dynamic LDS -> 2 blocks/CU
    (void)hipFuncSetAttribute((const void*)gen_actions_kernel,
                              hipFuncAttributeMaxDynamicSharedMemorySize,
                              (int)shbytes);
    hipLaunchKernelGGL(gen_actions_kernel, dim3(NBATCH), dim3(THREADS), shbytes, stream,
                       kx, pos, mask, scale, ev, bx, bk, ws, out);
}